// Round 3
// baseline (463.184 us; speedup 1.0000x reference)
//
#include <hip/hip_runtime.h>
#include <math.h>

#define C 256
#define NN 4096
#define SDIM 64                  // S = number of sentences (fixed 64)
#define T_INV 10.0f
#define NEG_IOU_TH 0.5f
#define SG 32                    // sentences per q-block
#define FL 2                     // flats per thread
#define QT (256 * FL)            // 512 flats per q-block
#define QTILES (NN / QT)         // 8
#define PAD 36                   // sT row stride in floats: 16B-aligned + bank-skewed

__device__ __forceinline__ float wave_reduce_sum(float v) {
    #pragma unroll
    for (int off = 32; off > 0; off >>= 1) v += __shfl_xor(v, off, 64);
    return v;
}

// Single fused kernel.
//  blocks [0,M): topk/inter-video (latency-heavy, start first)
//  blocks [M, M+256): inter-query GEMM+exp; 32 sentences staged raw in LDS
//    (broadcast ds_read_b128), post-hoc normalization, 2 flats/thread.
//  Last-finishing block computes the final loss.
__global__ void __launch_bounds__(256)
k_main(const float* __restrict__ vf, const float* __restrict__ sents,
       const float* __restrict__ iou2d, const float* __restrict__ iou2ds,
       const int* __restrict__ num_sentences, const int* __restrict__ num_targets,
       float* __restrict__ denomq, int* __restrict__ counter,
       float* __restrict__ pos, float* __restrict__ negiv, int* __restrict__ msent,
       float* __restrict__ out, int S, int B, int M, int ntot) {
    __shared__ float smem[C * PAD + SG];   // q: sT[c][PAD] + sn[SG]; m: tv|pd|ps
    __shared__ float red[4];
    __shared__ int   sidx[4];
    __shared__ float dw[4][SG];
    __shared__ int   bestflat;
    __shared__ int   amlast;

    int bid = blockIdx.x, tid = threadIdx.x;
    int lane = tid & 63, wave = tid >> 6;

    if (bid >= M) {
        // ================= inter-query part =================
        int qb   = bid - M;              // [0, 256)
        int tile = qb & (QTILES - 1);
        int b    = (qb >> 3) & 15;
        int g    = qb >> 7;              // sentence-group of 32

        int sb = 0;                      // local b2s
        for (int i = 0; i < b; ++i) sb += num_sentences[i];
        int ns = num_sentences[b];

        float* sT = smem;                // [C][PAD] raw sentences, transposed
        float* sn = smem + C * PAD;      // [SG] inv-norms
        if (tid < SG) sn[tid] = 0.f;
        __syncthreads();
        {   // stage 32 raw sentence rows transposed; fuse |s|^2
            int s  = tid >> 3;
            int c0 = (tid & 7) * 32;
            const float* sp = sents + (size_t)(g * SG + s) * C + c0;
            float ssq = 0.f;
            #pragma unroll
            for (int j = 0; j < 32; j += 4) {
                float4 x = *(const float4*)(sp + j);
                sT[(c0 + j + 0) * PAD + s] = x.x;
                sT[(c0 + j + 1) * PAD + s] = x.y;
                sT[(c0 + j + 2) * PAD + s] = x.z;
                sT[(c0 + j + 3) * PAD + s] = x.w;
                ssq += x.x*x.x + x.y*x.y + x.z*x.z + x.w*x.w;
            }
            atomicAdd(&sn[s], ssq);      // LDS atomic
        }
        __syncthreads();
        if (tid < SG) sn[tid] = 1.0f / fmaxf(sqrtf(sn[tid]), 1e-12f);
        __syncthreads();

        int flat0 = tile * QT + tid * FL;
        const float2* vp = (const float2*)(vf + (size_t)sb * C * NN + flat0);

        float accA[SG], accB[SG];
        #pragma unroll
        for (int i = 0; i < SG; ++i) { accA[i] = 0.f; accB[i] = 0.f; }
        float ssx = 0.f, ssy = 0.f;

        #pragma unroll 2
        for (int c = 0; c < C; ++c) {
            float2 v = vp[(size_t)c * (NN / 2)];   // coalesced
            ssx += v.x * v.x; ssy += v.y * v.y;
            const float4* sr = (const float4*)&sT[c * PAD];  // uniform -> broadcast
            #pragma unroll
            for (int k = 0; k < SG / 4; ++k) {
                float4 q4 = sr[k];
                accA[k*4+0] += q4.x * v.x;  accB[k*4+0] += q4.x * v.y;
                accA[k*4+1] += q4.y * v.x;  accB[k*4+1] += q4.y * v.y;
                accA[k*4+2] += q4.z * v.x;  accB[k*4+2] += q4.z * v.y;
                accA[k*4+3] += q4.w * v.x;  accB[k*4+3] += q4.w * v.y;
            }
        }

        int fA = flat0, fB = flat0 + 1;
        bool vA = ((fA & 63) >= (fA >> 6));      // triu(mask2d)
        bool vB = ((fB & 63) >= (fB >> 6));
        float sclA = (1.0f / fmaxf(sqrtf(ssx), 1e-12f)) * T_INV;
        float sclB = (1.0f / fmaxf(sqrtf(ssy), 1e-12f)) * T_INV;

        // own-batch positives excluded from the denominator
        unsigned long long bitsA = 0ull, bitsB = 0ull;
        for (int i = 0; i < ns; ++i) {
            const float* row = iou2d + (size_t)(sb + i) * NN;
            if (vA && row[fA] > NEG_IOU_TH) bitsA |= (1ull << (sb + i));
            if (vB && row[fB] > NEG_IOU_TH) bitsB |= (1ull << (sb + i));
        }
        unsigned mA = vA ? (unsigned)(bitsA >> (g * SG)) : 0xffffffffu;
        unsigned mB = vB ? (unsigned)(bitsB >> (g * SG)) : 0xffffffffu;

        #pragma unroll
        for (int i = 0; i < SG; ++i) {
            float inv = sn[i];
            float e = 0.f;
            if (!((mA >> i) & 1u)) e += expf(accA[i] * inv * sclA);
            if (!((mB >> i) & 1u)) e += expf(accB[i] * inv * sclB);
            accA[i] = e;
        }

        // log-transpose reduce within each 32-lane half (verified in v3)
        #pragma unroll
        for (int off = 16; off >= 1; off >>= 1) {
            int bsel = lane & off;
            #pragma unroll
            for (int i = 0; i < off; ++i) {
                float keep = bsel ? accA[off + i] : accA[i];
                float send = bsel ? accA[i] : accA[off + i];
                accA[i] = keep + __shfl_xor(send, off, 64);
            }
        }
        float tot_s = accA[0] + __shfl_xor(accA[0], 32, 64);
        if (lane < 32) dw[wave][lane] = tot_s;   // s = g*32 + lane
        __syncthreads();
        if (tid < SG)
            atomicAdd(&denomq[g * SG + tid],
                      dw[0][tid] + dw[1][tid] + dw[2][tid] + dw[3][tid]);
    } else {
        // ================= topk / inter-video part =================
        int m = bid;
        int s_m = 0;                     // local m2s
        {
            int acc2 = 0;
            for (int s2 = 0; s2 < SDIM; ++s2) {
                int nt = num_targets[s2];
                if (m >= acc2 && m < acc2 + nt) s_m = s2;
                acc2 += nt;
            }
        }

        float* tv = smem;                // [C] normalized v
        float* pd = smem + C;            // [256] dot partials
        float* ps = smem + C + 256;      // [256] |s|^2 partials

        float bv = -1e30f; int bi = NN;
        #pragma unroll
        for (int j = 0; j < NN / 256; ++j) {
            int flat = tid + j * 256;
            int rr = flat >> 6, cc2 = flat & 63;
            if (cc2 >= rr) {
                float val = iou2ds[(size_t)m * NN + flat];
                if (val > bv || (val == bv && flat < bi)) { bv = val; bi = flat; }
            }
        }
        #pragma unroll
        for (int off = 32; off > 0; off >>= 1) {
            float ov = __shfl_xor(bv, off, 64);
            int   oi = __shfl_xor(bi, off, 64);
            if (ov > bv || (ov == bv && oi < bi)) { bv = ov; bi = oi; }
        }
        if (lane == 0) { red[wave] = bv; sidx[wave] = bi; }
        __syncthreads();
        if (tid == 0) {
            float v0 = red[0]; int i0 = sidx[0];
            for (int w = 1; w < 4; ++w)
                if (red[w] > v0 || (red[w] == v0 && sidx[w] < i0)) { v0 = red[w]; i0 = sidx[w]; }
            bestflat = i0;
        }
        __syncthreads();
        int flat = bestflat;

        float v = vf[((size_t)s_m * C + tid) * NN + flat];
        float ssq = wave_reduce_sum(v * v);
        if (lane == 0) red[wave] = ssq;
        __syncthreads();
        float tot = red[0] + red[1] + red[2] + red[3];
        tv[tid] = v * (1.0f / fmaxf(sqrtf(tot), 1e-12f));
        __syncthreads();

        {   // dot(v_hat, s_raw) with fused |s|^2; 4 threads per sentence
            int s2 = tid >> 2, q = tid & 3;
            const float4* sp = (const float4*)(sents + (size_t)s2 * C + q * 64);
            const float4* tp = (const float4*)(tv + q * 64);
            float d = 0.f, ss = 0.f;
            #pragma unroll
            for (int j = 0; j < 16; ++j) {
                float4 x = sp[j];
                float4 t = tp[j];
                d  += x.x*t.x + x.y*t.y + x.z*t.z + x.w*t.w;
                ss += x.x*x.x + x.y*x.y + x.z*x.z + x.w*x.w;
            }
            pd[tid] = d; ps[tid] = ss;
        }
        __syncthreads();
        if (tid < SDIM) {
            float dt = pd[tid*4+0] + pd[tid*4+1] + pd[tid*4+2] + pd[tid*4+3];
            float st = ps[tid*4+0] + ps[tid*4+1] + ps[tid*4+2] + ps[tid*4+3];
            float dd = dt * (1.0f / fmaxf(sqrtf(st), 1e-12f));
            if (tid == s_m) atomicExch(&pos[m], dd);     // device-scope publish
            float e = (tid == s_m) ? 0.f : expf(dd * T_INV);
            e = wave_reduce_sum(e);
            if (tid == 0) { atomicExch(&negiv[m], e); atomicExch(&msent[m], s_m); }
        }
    }

    // ---- completion tail: last block to finish computes the final loss ----
    __syncthreads();   // drains this block's outstanding memory ops
    if (tid == 0) {
        __threadfence();
        int old = atomicAdd(counter, 1);
        amlast = (old == ntot - 1) ? 1 : 0;
    }
    __syncthreads();
    if (!amlast) return;

    __threadfence();
    float val = 0.f;
    for (int m2 = tid; m2 < M; m2 += 256) {
        int   sm2 = atomicAdd(&msent[m2], 0);              // coherent reads
        float pl  = atomicAdd(&pos[m2], 0.f) * T_INV;
        float niv = atomicAdd(&negiv[m2], 0.f);
        float dq  = atomicAdd(&denomq[sm2], 0.f);
        float pe = expf(pl);
        val += -(pl - logf(pe + niv)) + -(pl - logf(pe + dq));
    }
    val = wave_reduce_sum(val);
    if (lane == 0) dw[0][wave] = val;
    __syncthreads();
    if (tid == 0) out[0] = (dw[0][0] + dw[0][1] + dw[0][2] + dw[0][3]) / (float)M;
}

extern "C" void kernel_launch(void* const* d_in, const int* in_sizes, int n_in,
                              void* d_out, int out_size, void* d_ws, size_t ws_size,
                              hipStream_t stream) {
    const float* video_feats   = (const float*)d_in[0];
    const float* sents_feats   = (const float*)d_in[1];
    const float* iou2d         = (const float*)d_in[2];
    const float* iou2ds        = (const float*)d_in[3];
    const int*   num_sentences = (const int*)d_in[4];
    const int*   num_targets   = (const int*)d_in[5];
    // d_in[6] = mask2d: statically triu(ones(64,64)); computed as cc>=r in-kernel.

    const int S = in_sizes[2] / NN;   // 64
    const int B = in_sizes[4];        // 16
    const int M = in_sizes[3] / NN;   // 128

    float* denomq  = (float*)d_ws;              // [64]
    int*   counter = (int*)(denomq + SDIM);     // [1]
    float* pos     = (float*)(counter + 1);     // [M]
    float* negiv   = pos + M;                   // [M]
    int*   msent   = (int*)(negiv + M);         // [M]

    // zero denomq + counter (contiguous 260 B); everything else is published
    // via device-scope atomics before the completion counter fires.
    hipMemsetAsync(d_ws, 0, (SDIM + 1) * sizeof(float), stream);

    const int nq   = QTILES * B * (SDIM / SG);  // 8*16*2 = 256 q-blocks
    const int ntot = M + nq;                    // 384

    k_main<<<ntot, 256, 0, stream>>>(video_feats, sents_feats, iou2d, iou2ds,
                                     num_sentences, num_targets,
                                     denomq, counter, pos, negiv, msent,
                                     (float*)d_out, S, B, M, ntot);
}

// Round 4
// 404.186 us; speedup vs baseline: 1.1460x; 1.1460x over previous
//
#include <hip/hip_runtime.h>
#include <math.h>

#define C 256
#define NN 4096
#define SDIM 64                  // S = number of sentences (fixed 64)
#define T_INV 10.0f
#define NEG_IOU_TH 0.5f
#define SG 16                    // sentences per q-block
#define FL 2                     // flats per thread
#define QT (256 * FL)            // 512 flats per q-block
#define QTILES (NN / QT)         // 8

__device__ __forceinline__ float wave_reduce_sum(float v) {
    #pragma unroll
    for (int off = 32; off > 0; off >>= 1) v += __shfl_xor(v, off, 64);
    return v;
}

// --- prep: normalize sents -> sfT (c-major, s stride-1); block 0 builds
//     scatter maps and zeroes denomq + completion counter. ---------------
__global__ void k_prep(const float* __restrict__ sents,
                       const int* __restrict__ num_sentences,
                       const int* __restrict__ num_targets,
                       int B, int S, int M,
                       float* __restrict__ sfT, int* __restrict__ b2s,
                       int* __restrict__ s2b, int* __restrict__ m2s,
                       float* __restrict__ denomq, int* __restrict__ counter) {
    __shared__ float red[4];
    int s = blockIdx.x, tid = threadIdx.x;
    float v = sents[(size_t)s * C + tid];
    float ssq = wave_reduce_sum(v * v);
    int lane = tid & 63, wave = tid >> 6;
    if (lane == 0) red[wave] = ssq;
    __syncthreads();
    float tot = red[0] + red[1] + red[2] + red[3];
    sfT[(size_t)tid * S + s] = v * (1.0f / fmaxf(sqrtf(tot), 1e-12f));

    if (blockIdx.x == 0) {
        if (tid < S) denomq[tid] = 0.f;
        if (tid == 0) {
            *counter = 0;
            int acc = 0;
            for (int b = 0; b < B; ++b) {
                b2s[b] = acc;
                int nsb = num_sentences[b];
                for (int k = 0; k < nsb; ++k) s2b[acc + k] = b;
                acc += nsb;
            }
            int mi = 0;
            for (int si = 0; si < S; ++si) {
                int nt = num_targets[si];
                for (int k = 0; k < nt; ++k) m2s[mi++] = si;
            }
        }
    }
}

// --- main: blocks [0,M) = topk/inter-video (latency-heavy, start first);
//     blocks [M, M+512) = inter-query GEMM+exp.
//     Q-part: 2 flats/thread, 16 sentences/block -> 32 register accumulators
//     (v3-proven budget, no spill). Sentence operand = 4 contiguous uniform
//     float4 loads/channel from c-major normalized sfT. iou2d mask loads
//     only when the sentence-group intersects the video's batch (1 in 4).
//     Last-finishing block computes the final loss. ----------------------
__global__ void __launch_bounds__(256)
k_main(const float* __restrict__ vf, const float* __restrict__ iou2d,
       const float* __restrict__ iou2ds, const int* __restrict__ num_sentences,
       const float* __restrict__ sfT, const int* __restrict__ b2s,
       const int* __restrict__ m2s,
       float* __restrict__ pos, float* __restrict__ negiv,
       float* __restrict__ denomq, int* __restrict__ counter,
       float* __restrict__ out, int S, int B, int M, int nq, int ntot) {
    __shared__ float red[4];
    __shared__ int   sidx[4];
    __shared__ float dw[4][SG];
    __shared__ int   bestflat;
    __shared__ int   amlast;
    __shared__ float tv[C];        // m-part only
    __shared__ float sc4[256];     // m-part only

    int bid = blockIdx.x, tid = threadIdx.x;
    int lane = tid & 63, wave = tid >> 6;

    if (bid >= M) {
        // ================= inter-query part =================
        int qb   = bid - M;              // [0, 512)
        int tile = qb & (QTILES - 1);    // 8 flat-tiles
        int rem  = qb >> 3;
        int b    = rem & 15;             // 16 videos
        int g    = rem >> 4;             // 4 sentence-groups of 16
        int sb = b2s[b];
        int ns = num_sentences[b];

        int flat0 = tile * QT + tid * FL;
        const float2* vp = (const float2*)(vf + (size_t)sb * C * NN + flat0);
        // uniform sentence pointer: this group's 16 sentences, contiguous 64 B/ch
        const float4* sq = (const float4*)sfT + g * (SG / 4);

        float accA[SG], accB[SG];
        #pragma unroll
        for (int i = 0; i < SG; ++i) { accA[i] = 0.f; accB[i] = 0.f; }
        float ssx = 0.f, ssy = 0.f;

        #pragma unroll 2
        for (int c = 0; c < C; ++c) {
            float2 v = vp[(size_t)c * (NN / 2)];   // coalesced 8 B/lane
            ssx += v.x * v.x; ssy += v.y * v.y;
            const float4* sc = sq + (size_t)c * (SDIM / 4);
            #pragma unroll
            for (int k = 0; k < SG / 4; ++k) {
                float4 q4 = sc[k];                 // uniform, contiguous
                accA[k*4+0] += q4.x * v.x;  accB[k*4+0] += q4.x * v.y;
                accA[k*4+1] += q4.y * v.x;  accB[k*4+1] += q4.y * v.y;
                accA[k*4+2] += q4.z * v.x;  accB[k*4+2] += q4.z * v.y;
                accA[k*4+3] += q4.w * v.x;  accB[k*4+3] += q4.w * v.y;
            }
        }

        int fA = flat0, fB = flat0 + 1;
        bool vA = ((fA & 63) >= (fA >> 6));      // triu(mask2d)
        bool vB = ((fB & 63) >= (fB >> 6));
        float sclA = (1.0f / fmaxf(sqrtf(ssx), 1e-12f)) * T_INV;
        float sclB = (1.0f / fmaxf(sqrtf(ssy), 1e-12f)) * T_INV;

        // own-batch positives excluded; only if batch intersects this group
        unsigned mA = vA ? 0u : 0xffffu;
        unsigned mB = vB ? 0u : 0xffffu;
        int lo = max(sb, g * SG), hi = min(sb + ns, g * SG + SG);
        for (int s_abs = lo; s_abs < hi; ++s_abs) {
            float2 io = *(const float2*)(iou2d + (size_t)s_abs * NN + flat0);
            unsigned bit = 1u << (s_abs - g * SG);
            if (io.x > NEG_IOU_TH) mA |= bit;
            if (io.y > NEG_IOU_TH) mB |= bit;
        }

        float e[SG];
        #pragma unroll
        for (int i = 0; i < SG; ++i) {
            float v = 0.f;
            if (!((mA >> i) & 1u)) v += expf(accA[i] * sclA);
            if (!((mB >> i) & 1u)) v += expf(accB[i] * sclB);
            e[i] = v;
        }

        // log-transpose reduce within each 16-lane group (pattern verified v3)
        #pragma unroll
        for (int off = 8; off >= 1; off >>= 1) {
            int bsel = lane & off;
            #pragma unroll
            for (int i = 0; i < off; ++i) {
                float keep = bsel ? e[off + i] : e[i];
                float send = bsel ? e[i] : e[off + i];
                e[i] = keep + __shfl_xor(send, off, 64);
            }
        }
        float x = e[0];                       // lane l: sentence (l&15), 16-group sum
        x += __shfl_xor(x, 16, 64);
        x += __shfl_xor(x, 32, 64);           // full-wave per-sentence sum
        if (lane < SG) dw[wave][lane] = x;    // s = g*16 + lane
        __syncthreads();
        if (tid < SG)
            atomicAdd(&denomq[g * SG + tid],
                      dw[0][tid] + dw[1][tid] + dw[2][tid] + dw[3][tid]);
    } else {
        // ================= topk / inter-video part =================
        int m = bid;
        int s_m = m2s[m];

        float bv = -1e30f; int bi = NN;
        #pragma unroll
        for (int j = 0; j < NN / 256; ++j) {
            int flat = tid + j * 256;
            int rr = flat >> 6, cc = flat & 63;
            if (cc >= rr) {
                float val = iou2ds[(size_t)m * NN + flat];
                if (val > bv || (val == bv && flat < bi)) { bv = val; bi = flat; }
            }
        }
        #pragma unroll
        for (int off = 32; off > 0; off >>= 1) {
            float ov = __shfl_xor(bv, off, 64);
            int   oi = __shfl_xor(bi, off, 64);
            if (ov > bv || (ov == bv && oi < bi)) { bv = ov; bi = oi; }
        }
        if (lane == 0) { red[wave] = bv; sidx[wave] = bi; }
        __syncthreads();
        if (tid == 0) {
            float v0 = red[0]; int i0 = sidx[0];
            for (int w = 1; w < 4; ++w)
                if (red[w] > v0 || (red[w] == v0 && sidx[w] < i0)) { v0 = red[w]; i0 = sidx[w]; }
            bestflat = i0;
        }
        __syncthreads();
        int flat = bestflat;

        float v = vf[((size_t)s_m * C + tid) * NN + flat];
        float ssq = wave_reduce_sum(v * v);
        if (lane == 0) red[wave] = ssq;
        __syncthreads();
        float tot = red[0] + red[1] + red[2] + red[3];
        tv[tid] = v * (1.0f / fmaxf(sqrtf(tot), 1e-12f));
        __syncthreads();

        {
            int s = tid & 63, cg = tid >> 6;
            float d = 0.f;
            for (int j = 0; j < 64; ++j) {
                int c2 = cg * 64 + j;
                d += tv[c2] * sfT[(size_t)c2 * S + s];
            }
            sc4[cg * 64 + s] = d;
        }
        __syncthreads();
        if (tid < 64) {
            float d = sc4[tid] + sc4[64 + tid] + sc4[128 + tid] + sc4[192 + tid];
            if (tid == s_m) atomicExch(&pos[m], d);   // device-scope publish
            float e2 = (tid == s_m) ? 0.f : expf(d * T_INV);
            e2 = wave_reduce_sum(e2);
            if (tid == 0) atomicExch(&negiv[m], e2);  // device-scope publish
        }
    }

    // ---- completion tail: last block to finish computes the final loss ----
    __syncthreads();   // drains this block's outstanding memory ops
    if (tid == 0) {
        __threadfence();
        int old = atomicAdd(counter, 1);
        amlast = (old == ntot - 1) ? 1 : 0;
    }
    __syncthreads();
    if (!amlast) return;

    __threadfence();
    float val = 0.f;
    for (int m = tid; m < M; m += 256) {
        int s = m2s[m];
        float pl  = atomicAdd(&pos[m], 0.f) * T_INV;       // coherent reads
        float niv = atomicAdd(&negiv[m], 0.f);
        float dq  = atomicAdd(&denomq[s], 0.f);
        float pe = expf(pl);
        val += -(pl - logf(pe + niv)) + -(pl - logf(pe + dq));
    }
    val = wave_reduce_sum(val);
    if (lane == 0) dw[0][wave] = val;
    __syncthreads();
    if (tid == 0) out[0] = (dw[0][0] + dw[0][1] + dw[0][2] + dw[0][3]) / (float)M;
}

extern "C" void kernel_launch(void* const* d_in, const int* in_sizes, int n_in,
                              void* d_out, int out_size, void* d_ws, size_t ws_size,
                              hipStream_t stream) {
    const float* video_feats   = (const float*)d_in[0];
    const float* sents_feats   = (const float*)d_in[1];
    const float* iou2d         = (const float*)d_in[2];
    const float* iou2ds        = (const float*)d_in[3];
    const int*   num_sentences = (const int*)d_in[4];
    const int*   num_targets   = (const int*)d_in[5];
    // d_in[6] = mask2d: statically triu(ones(64,64)); computed as cc>=r in-kernel.

    const int S = in_sizes[2] / NN;   // 64
    const int B = in_sizes[4];        // 16
    const int M = in_sizes[3] / NN;   // 128

    float* sfT    = (float*)d_ws;              // C*S
    float* pos    = sfT + (size_t)C * 64;
    float* negiv  = pos + M;
    float* denomq = negiv + M;
    int*   b2s    = (int*)(denomq + S);
    int*   s2b    = b2s + B;
    int*   m2s    = s2b + S;
    int*   counter = m2s + M;

    const int nq   = QTILES * B * (SDIM / SG);   // 8*16*4 = 512 q-blocks
    const int ntot = M + nq;                     // 640

    k_prep<<<S, C, 0, stream>>>(sents_feats, num_sentences, num_targets,
                                B, S, M, sfT, b2s, s2b, m2s, denomq, counter);
    k_main<<<ntot, 256, 0, stream>>>(video_feats, iou2d, iou2ds, num_sentences,
                                     sfT, b2s, m2s, pos, negiv, denomq, counter,
                                     (float*)d_out, S, B, M, nq, ntot);
}

// Round 5
// 367.234 us; speedup vs baseline: 1.2613x; 1.1006x over previous
//
#include <hip/hip_runtime.h>
#include <math.h>

#define C 256
#define NN 4096
#define SDIM 64                  // S = number of sentences (fixed 64)
#define T_INV 10.0f
#define NEG_IOU_TH 0.5f
#define SG 32                    // sentences per q-block
#define QTILE 256                // flats per q-block (1 per thread)
#define QTILES (NN / QTILE)      // 16

__device__ __forceinline__ float wave_reduce_sum(float v) {
    #pragma unroll
    for (int off = 32; off > 0; off >>= 1) v += __shfl_xor(v, off, 64);
    return v;
}

// --- prep: normalize sents -> sfT (c-major, s stride-1); block 0 builds
//     scatter maps (parallel prefix per thread) and zeroes denomq+counter. --
__global__ void k_prep(const float* __restrict__ sents,
                       const int* __restrict__ num_sentences,
                       const int* __restrict__ num_targets,
                       int B, int S, int M,
                       float* __restrict__ sfT, int* __restrict__ b2s,
                       int* __restrict__ s2b, int* __restrict__ m2s,
                       float* __restrict__ denomq, int* __restrict__ counter) {
    __shared__ float red[4];
    int s = blockIdx.x, tid = threadIdx.x;
    float v = sents[(size_t)s * C + tid];
    float ssq = wave_reduce_sum(v * v);
    int lane = tid & 63, wave = tid >> 6;
    if (lane == 0) red[wave] = ssq;
    __syncthreads();
    float tot = red[0] + red[1] + red[2] + red[3];
    sfT[(size_t)tid * S + s] = v * (1.0f / fmaxf(sqrtf(tot), 1e-12f));

    if (blockIdx.x == 0) {
        if (tid < S) denomq[tid] = 0.f;
        if (tid == 0) *counter = 0;
        if (tid < B) {                       // b2s + s2b, one thread per batch
            int acc = 0;
            for (int i = 0; i < tid; ++i) acc += num_sentences[i];
            b2s[tid] = acc;
            int nsb = num_sentences[tid];
            for (int k = 0; k < nsb; ++k) s2b[acc + k] = tid;
        }
        if (tid >= 64 && tid < 64 + S) {     // m2s, one thread per sentence
            int si = tid - 64;
            int acc = 0;
            for (int i = 0; i < si; ++i) acc += num_targets[i];
            int nt = num_targets[si];
            for (int k = 0; k < nt; ++k) m2s[acc + k] = si;
        }
    }
}

// --- main: blocks [0,M) = topk/inter-video (latency-heavy, start first);
//     blocks [M, M+512) = inter-query GEMM+exp.
//     Q-part: 1 flat/thread, 32 sentences/block, sentence operand via
//     wave-uniform loads (SGPR), unroll 8 for 8 vf loads in flight.
//     Last-finishing block computes the final loss. ----------------------
__global__ void __launch_bounds__(256)
k_main(const float* __restrict__ vf, const float* __restrict__ iou2d,
       const float* __restrict__ iou2ds, const int* __restrict__ num_sentences,
       const float* __restrict__ sfT, const int* __restrict__ b2s,
       const int* __restrict__ m2s,
       float* __restrict__ pos, float* __restrict__ negiv,
       float* __restrict__ denomq, int* __restrict__ counter,
       float* __restrict__ out, int S, int B, int M, int nq, int ntot) {
    __shared__ float red[4];
    __shared__ int   sidx[4];
    __shared__ float dw[4][SDIM];
    __shared__ int   bestflat;
    __shared__ int   amlast;
    __shared__ float tv[C];        // m-part only
    __shared__ float sc4[256];     // m-part only

    int bid = blockIdx.x, tid = threadIdx.x;
    int lane = tid & 63, wave = tid >> 6;

    if (bid >= M) {
        // ================= inter-query part =================
        int qb   = bid - M;              // [0, 512)
        int tile = qb & (QTILES - 1);    // 16 flat-tiles
        int rem  = qb >> 4;
        int b    = rem & 15;             // 16 videos
        int g    = rem >> 4;             // 2 sentence-groups of 32
        int sb = b2s[b];
        int ns = num_sentences[b];

        int flat = tile * QTILE + tid;   // this thread's proposal
        const float* vp = vf + (size_t)sb * C * NN + flat;
        // wave-uniform sentence pointer: float4 chunks of this group's 32 s
        const float4* sq = (const float4*)sfT + (size_t)g * 8;

        float acc[SG];                   // fully-unrolled -> stays in VGPRs
        #pragma unroll
        for (int s = 0; s < SG; ++s) acc[s] = 0.f;
        float ssq = 0.f;

        #pragma unroll 8
        for (int c = 0; c < C; ++c) {
            float v = vp[(size_t)c * NN];          // coalesced vector load
            ssq += v * v;
            const float4* sqc = sq + (size_t)c * (SDIM / 4);
            #pragma unroll
            for (int k = 0; k < SG / 4; ++k) {
                float4 q4 = sqc[k];                // uniform -> s_load
                acc[k * 4 + 0] += q4.x * v;
                acc[k * 4 + 1] += q4.y * v;
                acc[k * 4 + 2] += q4.z * v;
                acc[k * 4 + 3] += q4.w * v;
            }
        }

        int r = flat >> 6, cc = flat & 63;
        bool valid = (cc >= r);          // triu(mask2d)
        float scale = (1.0f / fmaxf(sqrtf(ssq), 1e-12f)) * T_INV;

        // own-batch positives are excluded from the denominator
        unsigned long long excl = 0ull;
        for (int i = 0; i < ns; ++i)
            if (iou2d[(size_t)(sb + i) * NN + flat] > NEG_IOU_TH)
                excl |= (1ull << (sb + i));
        if (!valid) excl = ~0ull;        // invalid flat contributes nothing

        unsigned mask32 = (unsigned)(excl >> (g * 32));
        #pragma unroll
        for (int i = 0; i < SG; ++i)
            acc[i] = ((mask32 >> i) & 1u) ? 0.f : expf(acc[i] * scale);

        // log-transpose reduce within each 32-lane half:
        // after this, lane l holds sum over its half's lanes of acc[l&31]
        #pragma unroll
        for (int off = 16; off >= 1; off >>= 1) {
            int bsel = lane & off;
            #pragma unroll
            for (int i = 0; i < off; ++i) {
                float keep = bsel ? acc[off + i] : acc[i];
                float send = bsel ? acc[i] : acc[off + i];
                acc[i] = keep + __shfl_xor(send, off, 64);
            }
        }
        float tot_s = acc[0] + __shfl_xor(acc[0], 32, 64);  // combine halves
        if (lane < 32) dw[wave][lane] = tot_s;   // s = g*32 + lane
        __syncthreads();
        if (tid < 32)
            atomicAdd(&denomq[g * 32 + tid],
                      dw[0][tid] + dw[1][tid] + dw[2][tid] + dw[3][tid]);
    } else {
        // ================= topk / inter-video part =================
        int m = bid;
        int s_m = m2s[m];

        float bv = -1e30f; int bi = NN;
        #pragma unroll
        for (int j = 0; j < NN / 256; ++j) {
            int flat = tid + j * 256;
            int rr = flat >> 6, cc = flat & 63;
            if (cc >= rr) {
                float val = iou2ds[(size_t)m * NN + flat];
                if (val > bv || (val == bv && flat < bi)) { bv = val; bi = flat; }
            }
        }
        #pragma unroll
        for (int off = 32; off > 0; off >>= 1) {
            float ov = __shfl_xor(bv, off, 64);
            int   oi = __shfl_xor(bi, off, 64);
            if (ov > bv || (ov == bv && oi < bi)) { bv = ov; bi = oi; }
        }
        if (lane == 0) { red[wave] = bv; sidx[wave] = bi; }
        __syncthreads();
        if (tid == 0) {
            float v0 = red[0]; int i0 = sidx[0];
            for (int w = 1; w < 4; ++w)
                if (red[w] > v0 || (red[w] == v0 && sidx[w] < i0)) { v0 = red[w]; i0 = sidx[w]; }
            bestflat = i0;
        }
        __syncthreads();
        int flat = bestflat;

        float v = vf[((size_t)s_m * C + tid) * NN + flat];
        float ssq = wave_reduce_sum(v * v);
        if (lane == 0) red[wave] = ssq;
        __syncthreads();
        float tot = red[0] + red[1] + red[2] + red[3];
        tv[tid] = v * (1.0f / fmaxf(sqrtf(tot), 1e-12f));
        __syncthreads();

        {
            int s = tid & 63, cg = tid >> 6;
            float d = 0.f;
            for (int j = 0; j < 64; ++j) {
                int c2 = cg * 64 + j;
                d += tv[c2] * sfT[(size_t)c2 * S + s];
            }
            sc4[cg * 64 + s] = d;
        }
        __syncthreads();
        if (tid < 64) {
            float d = sc4[tid] + sc4[64 + tid] + sc4[128 + tid] + sc4[192 + tid];
            if (tid == s_m) atomicExch(&pos[m], d);   // device-scope publish
            float e = (tid == s_m) ? 0.f : expf(d * T_INV);
            e = wave_reduce_sum(e);
            if (tid == 0) atomicExch(&negiv[m], e);   // device-scope publish
        }
    }

    // ---- completion tail: last block to finish computes the final loss ----
    __syncthreads();   // drains this block's outstanding memory ops
    if (tid == 0) {
        __threadfence();
        int old = atomicAdd(counter, 1);
        amlast = (old == ntot - 1) ? 1 : 0;
    }
    __syncthreads();
    if (!amlast) return;

    __threadfence();
    float val = 0.f;
    for (int m = tid; m < M; m += 256) {
        int s = m2s[m];
        float pl  = atomicAdd(&pos[m], 0.f) * T_INV;       // coherent reads
        float niv = atomicAdd(&negiv[m], 0.f);
        float dq  = atomicAdd(&denomq[s], 0.f);
        float pe = expf(pl);
        val += -(pl - logf(pe + niv)) + -(pl - logf(pe + dq));
    }
    val = wave_reduce_sum(val);
    if (lane == 0) dw[0][wave] = val;
    __syncthreads();
    if (tid == 0) out[0] = (dw[0][0] + dw[0][1] + dw[0][2] + dw[0][3]) / (float)M;
}

extern "C" void kernel_launch(void* const* d_in, const int* in_sizes, int n_in,
                              void* d_out, int out_size, void* d_ws, size_t ws_size,
                              hipStream_t stream) {
    const float* video_feats   = (const float*)d_in[0];
    const float* sents_feats   = (const float*)d_in[1];
    const float* iou2d         = (const float*)d_in[2];
    const float* iou2ds        = (const float*)d_in[3];
    const int*   num_sentences = (const int*)d_in[4];
    const int*   num_targets   = (const int*)d_in[5];
    // d_in[6] = mask2d: statically triu(ones(64,64)); computed as cc>=r in-kernel.

    const int S = in_sizes[2] / NN;   // 64
    const int B = in_sizes[4];        // 16
    const int M = in_sizes[3] / NN;   // 128

    float* sfT    = (float*)d_ws;              // C*S
    float* pos    = sfT + (size_t)C * 64;
    float* negiv  = pos + M;
    float* denomq = negiv + M;
    int*   b2s    = (int*)(denomq + S);
    int*   s2b    = b2s + B;
    int*   m2s    = s2b + S;
    int*   counter = m2s + M;

    const int nq   = QTILES * B * (SDIM / SG);   // 16*16*2 = 512 q-blocks
    const int ntot = M + nq;                     // 640

    k_prep<<<S, C, 0, stream>>>(sents_feats, num_sentences, num_targets,
                                B, S, M, sfT, b2s, s2b, m2s, denomq, counter);
    k_main<<<ntot, 256, 0, stream>>>(video_feats, iou2d, iou2ds, num_sentences,
                                     sfT, b2s, m2s, pos, negiv, denomq, counter,
                                     (float*)d_out, S, B, M, nq, ntot);
}